// Round 7
// baseline (309.289 us; speedup 1.0000x reference)
//
#include <hip/hip_runtime.h>
#include <hip/hip_bf16.h>
#include <cstddef>

#define T_LEN 50000

typedef __attribute__((ext_vector_type(8))) short bf16x8;
typedef __attribute__((ext_vector_type(4))) float f32x4;

__device__ __forceinline__ float sp_(float x){ return (x > 20.f) ? x : log1pf(expf(x)); }
__device__ __forceinline__ float gelu1(float x){ return 0.5f*x*(1.f + erff(x*0.7071067811865475f)); }

// ---------------- kernel 0: wbf convert + WnL/SmLUT tables (pure fn of syn) ----------------
__global__ void k_cvtw(const float* __restrict__ wproj, const float* __restrict__ syn,
                       __hip_bfloat16* __restrict__ wbf, float* __restrict__ wn_g,
                       float* __restrict__ sm_g)
{
    int idx = blockIdx.x*256 + threadIdx.x;
    if (idx < 160*128) {
        int d = idx >> 7, i = idx & 127;
        float v = (i < 100) ? wproj[d*100 + i] : 0.f;
        wbf[idx] = __float2bfloat16(v);
    }
    if (blockIdx.x == 0 && threadIdx.x < 16) {
        // each of 16 threads recomputes the full WnL (identical float op order to R2)
        float wn[16];
        #pragma unroll
        for (int m=0;m<4;++m){
            float w0=sp_(syn[m*4+0]), w1=sp_(syn[m*4+1]);
            float w2=sp_(syn[m*4+2]), w3=sp_(syn[m*4+3]);
            float inv = 1.f/fmaxf(w0+w1+w2+w3, 1e-6f);
            wn[m*4+0]=w0*inv; wn[m*4+1]=w1*inv; wn[m*4+2]=w2*inv; wn[m*4+3]=w3*inv;
        }
        wn_g[threadIdx.x] = wn[threadIdx.x];
        const int mk = threadIdx.x;
        #pragma unroll
        for (int m=0;m<4;++m){
            float a = 0.f;
            #pragma unroll
            for (int c=0;c<4;++c) if (mk & (1<<c)) a += wn[m*4+c];
            sm_g[mk*4+m] = fminf(a, 1.f);
        }
    }
}

// ---------------- kernel 1 phase 2 body: direct-from-global streaming conv ------------------
// GUARD=true only for boundary tiles (0, 49). Arithmetic identical to R2's phase 2.
template<bool GUARD>
__device__ __forceinline__ void phase2_body(
    const float4* __restrict__ X4, const float4* __restrict__ M4,
    int t0, int tid,
    const float* __restrict__ w_env, const float* __restrict__ w_bur,
    const float* __restrict__ wn,
    float4* s1b, unsigned char* maskb)
{
    float4 env[4], bur[4], xk[4];
    #pragma unroll
    for (int j=0;j<4;++j){ env[j]=make_float4(0,0,0,0); bur[j]=make_float4(0,0,0,0); }
    float4 xprev = make_float4(0,0,0,0);
    const int base  = 4*tid;
    const int gbase = t0 - 4 + 4*tid;
    #pragma unroll
    for (int s = -12; s <= 15; ++s) {
        const int g = gbase + s;
        float4 a = make_float4(0,0,0,0), m = make_float4(0,0,0,0);
        if (!GUARD || (g >= 0 && g < T_LEN)) { a = X4[g]; m = M4[g]; }
        const float4 xc = make_float4(a.x*m.x, a.y*m.y, a.z*m.z, a.w*m.w);
        const float4 ax = make_float4(fabsf(xc.x),fabsf(xc.y),fabsf(xc.z),fabsf(xc.w));
        if (s >= -4 && s <= 7) {
            float4 dx;
            if (GUARD && (g <= 0 || g >= T_LEN)) dx = make_float4(0,0,0,0);
            else dx = make_float4(xc.x-xprev.x, xc.y-xprev.y, xc.z-xprev.z, xc.w-xprev.w);
            const float4 adx = make_float4(fabsf(dx.x),fabsf(dx.y),fabsf(dx.z),fabsf(dx.w));
            #pragma unroll
            for (int j=0;j<4;++j) {
                int bk = s + 4 - j;
                if (bk >= 0 && bk < 9) {
                    float b0=w_bur[bk], b1=w_bur[9+bk], b2=w_bur[18+bk], b3=w_bur[27+bk];
                    bur[j].x = fmaf(b0, adx.x, bur[j].x);
                    bur[j].y = fmaf(b1, adx.y, bur[j].y);
                    bur[j].z = fmaf(b2, adx.z, bur[j].z);
                    bur[j].w = fmaf(b3, adx.w, bur[j].w);
                }
            }
        }
        #pragma unroll
        for (int j=0;j<4;++j) {
            int k = s + 12 - j;
            if (k >= 0 && k < 25) {
                float e0=w_env[k], e1=w_env[25+k], e2=w_env[50+k], e3=w_env[75+k];
                env[j].x = fmaf(e0, ax.x, env[j].x);
                env[j].y = fmaf(e1, ax.y, env[j].y);
                env[j].z = fmaf(e2, ax.z, env[j].z);
                env[j].w = fmaf(e3, ax.w, env[j].w);
            }
        }
        if (s >= 0 && s <= 3) {
            xk[s] = xc;
            const int lt = base - 4 + s;      // local t of output j=s
            if (lt >= 0 && lt < 1000) {
                unsigned mk = (m.x>0.f?1u:0u) | (m.y>0.f?2u:0u) | (m.z>0.f?4u:0u) | (m.w>0.f?8u:0u);
                maskb[lt] = (unsigned char)mk;
            }
        }
        xprev = xc;
    }
    #pragma unroll
    for (int j=0;j<4;++j) {
        const int g = gbase + j;
        float4 xm = make_float4(
            0.9f*env[j].x + 0.6f*bur[j].x + 0.2f*xk[j].x,
            0.9f*env[j].y + 0.6f*bur[j].y + 0.2f*xk[j].y,
            0.9f*env[j].z + 0.6f*bur[j].z + 0.2f*xk[j].z,
            0.9f*env[j].w + 0.6f*bur[j].w + 0.2f*xk[j].w);
        float4 out = make_float4(0,0,0,0);
        if (g >= 0 && g < T_LEN) {
            out.x = wn[0]*xm.x  + wn[1]*xm.y  + wn[2]*xm.z  + wn[3]*xm.w;
            out.y = wn[4]*xm.x  + wn[5]*xm.y  + wn[6]*xm.z  + wn[7]*xm.w;
            out.z = wn[8]*xm.x  + wn[9]*xm.y  + wn[10]*xm.z + wn[11]*xm.w;
            out.w = wn[12]*xm.x + wn[13]*xm.y + wn[14]*xm.z + wn[15]*xm.w;
        }
        const int ls = base + j;
        s1b[ls + (ls>>3)] = out;
    }
}

// ---------------- kernel 1: preprocessing chain -> xs bf16 [patch][128] + m_patch ----------
// Direct-from-global phase 2 (no x LDS tile, no staging barrier). 256 threads, 1000-t tile.
// LDS: s1b 18144 + maskb 1000 + abf 10240 = ~29.4 KB. Two barriers total.
__global__ __launch_bounds__(256) void k_pre(
    const float* __restrict__ X, const float* __restrict__ Mq,
    const float* __restrict__ w_env, const float* __restrict__ w_bur,
    const float* __restrict__ wdw, const float* __restrict__ wpw,
    const float* __restrict__ wn_g, const float* __restrict__ sm_g,
    __hip_bfloat16* __restrict__ xs_out, float* __restrict__ mpatch)
{
    __shared__ float4 s1b[1134];   // S1 tile, t in [t0-4, t0+1004), +1-per-8 padded
    __shared__ unsigned char maskb[1000];
    __shared__ __align__(16) __hip_bfloat16 abf[40*128];  // A-layout tile: [patch][i=m*25+k]

    const int tid  = threadIdx.x;
    const int b    = blockIdx.x / 50;
    const int tile = blockIdx.x % 50;
    const int t0   = tile * 1000;

    const float4* X4 = (const float4*)X + (size_t)b * T_LEN;
    const float4* M4 = (const float4*)Mq + (size_t)b * T_LEN;

    // zero abf K-pad (i in [100,128)) — covered by the p3->p4 barrier
    for (int idx = tid; idx < 40*28; idx += 256) {
        int p = idx / 28, i = 100 + idx % 28;
        abf[p*128 + i] = __float2bfloat16(0.f);
    }

    // ---- phase 2 (merged with old phase 1): stream x=X*M from global, conv, write s1b ----
    if (tid < 252) {
        const bool interior = (tile != 0) && (tile != 49);
        if (interior) phase2_body<false>(X4, M4, t0, tid, w_env, w_bur, wn_g, s1b, maskb);
        else          phase2_body<true >(X4, M4, t0, tid, w_env, w_bur, wn_g, s1b, maskb);
    }
    __syncthreads();

    // ---- phase 3: pre-dw + gelu + pw + gelu, * Sm -> abf (bf16, A-layout) ----
    if (tid < 250) {
        const float4* sm4 = (const float4*)sm_g;   // 16-entry LUT, L1-hot
        float4 s2a[4];
        #pragma unroll
        for (int j=0;j<4;++j) s2a[j]=make_float4(0,0,0,0);
        const int base = 4*tid;
        #pragma unroll
        for (int s = -4; s <= 7; ++s) {
            int ls = base + s + 4;
            float4 sc = s1b[ls + (ls>>3)];
            #pragma unroll
            for (int j=0;j<4;++j) {
                int k = s + 4 - j;
                if (k >= 0 && k < 9) {
                    float d0=wdw[k], d1=wdw[9+k], d2=wdw[18+k], d3=wdw[27+k];
                    s2a[j].x = fmaf(d0, sc.x, s2a[j].x);
                    s2a[j].y = fmaf(d1, sc.y, s2a[j].y);
                    s2a[j].z = fmaf(d2, sc.z, s2a[j].z);
                    s2a[j].w = fmaf(d3, sc.w, s2a[j].w);
                }
            }
        }
        #pragma unroll
        for (int j=0;j<4;++j) {
            int t = base + j;              // local t in [0,1000)
            float g0 = gelu1(s2a[j].x), g1 = gelu1(s2a[j].y);
            float g2 = gelu1(s2a[j].z), g3 = gelu1(s2a[j].w);
            float4 sm = sm4[maskb[t]];
            int p = t / 25, k = t % 25;
            float smv[4] = {sm.x, sm.y, sm.z, sm.w};
            #pragma unroll
            for (int o=0;o<4;++o) {
                float v = wpw[o*4+0]*g0 + wpw[o*4+1]*g1 + wpw[o*4+2]*g2 + wpw[o*4+3]*g3;
                abf[p*128 + o*25 + k] = __float2bfloat16(gelu1(v) * smv[o]);
            }
        }
    }
    __syncthreads();

    // ---- phase 4: copy abf -> global (coalesced), m_patch from mask bits ----
    {
        const float4* src = (const float4*)abf;
        float4* dst = (float4*)(xs_out + (size_t)(b*2000 + tile*40)*128);
        #pragma unroll
        for (int it = 0; it < 3; ++it) {
            int idx = tid + it*256;
            if (idx < 640) dst[idx] = src[idx];
        }
    }
    // softplus > 0 strictly => all normalized W entries > 0 => sum_m Sm[t] > 0 <=> mask[t] != 0
    if (tid < 40) {
        int cnt = 0;
        #pragma unroll
        for (int k=0;k<25;++k) cnt += (maskb[tid*25 + k] != 0) ? 1 : 0;
        mpatch[(size_t)b*2000 + tile*40 + tid] = (cnt >= 3) ? 1.f : 0.f;
    }
}

// ---------------- kernel 2: MFMA patch projection (M=128000, N=160, K=128) + LayerNorm ----
// R2-verified version, byte-identical. Operand-swapped MFMA; float4 stores.
__global__ __launch_bounds__(256) void k_proj(
    const __hip_bfloat16* __restrict__ wbf, const __hip_bfloat16* __restrict__ xsg,
    const float* __restrict__ gamma, const float* __restrict__ beta,
    float* __restrict__ hout)
{
    __shared__ __align__(16) unsigned short Wl[160*136];  // [d][K=128 pad 136]
    __shared__ __align__(16) unsigned short Al[64*136];   // [patch][K=128 pad 136]
    const int tid  = threadIdx.x;
    const int wv   = tid >> 6, lane = tid & 63;
    const int n    = lane & 15, quad = lane >> 4;

    {
        const float4* wg = (const float4*)wbf;
        #pragma unroll
        for (int it = 0; it < 10; ++it) {
            int idx = tid + it*256;
            int row = idx >> 4, cir = idx & 15;
            *(float4*)(Wl + row*136 + cir*8) = wg[idx];
        }
    }

    for (int bt = 0; bt < 2; ++bt) {
        const int p0 = (blockIdx.x*2 + bt) * 64;
        __syncthreads();   // covers Wl visibility at bt=0; Al reuse at bt=1
        {
            const float4* ag = (const float4*)(xsg + (size_t)p0*128);
            #pragma unroll
            for (int it = 0; it < 4; ++it) {
                int idx = tid + it*256;
                int row = idx >> 4, cir = idx & 15;
                *(float4*)(Al + row*136 + cir*8) = ag[idx];
            }
        }
        __syncthreads();

        f32x4 acc[10];
        #pragma unroll
        for (int t = 0; t < 10; ++t) acc[t] = (f32x4){0.f,0.f,0.f,0.f};
        #pragma unroll
        for (int kk = 0; kk < 4; ++kk) {
            bf16x8 pf = *(const bf16x8*)(Al + (wv*16 + n)*136 + kk*32 + quad*8);  // patch frag (B)
            #pragma unroll
            for (int t = 0; t < 10; ++t) {
                bf16x8 wf = *(const bf16x8*)(Wl + (t*16 + n)*136 + kk*32 + quad*8); // W frag (A)
                acc[t] = __builtin_amdgcn_mfma_f32_16x16x32_bf16(wf, pf, acc[t], 0, 0, 0);
            }
        }

        float s = 0.f;
        #pragma unroll
        for (int t = 0; t < 10; ++t) {
            #pragma unroll
            for (int r = 0; r < 4; ++r) s += acc[t][r];
        }
        s += __shfl_xor(s, 16, 64); s += __shfl_xor(s, 32, 64);
        const float mu = s * (1.f/160.f);
        float q = 0.f;
        #pragma unroll
        for (int t = 0; t < 10; ++t) {
            #pragma unroll
            for (int r = 0; r < 4; ++r) { float dv = acc[t][r] - mu; q = fmaf(dv, dv, q); }
        }
        q += __shfl_xor(q, 16, 64); q += __shfl_xor(q, 32, 64);
        const float rs = rsqrtf(q * (1.f/160.f) + 1e-5f);

        const int prow = p0 + wv*16 + n;
        float* hp = hout + (size_t)prow*160;
        #pragma unroll
        for (int t = 0; t < 10; ++t) {
            const float4 g  = *(const float4*)(gamma + t*16 + quad*4);
            const float4 be = *(const float4*)(beta  + t*16 + quad*4);
            float4 o;
            o.x = (acc[t][0] - mu)*rs*g.x + be.x;
            o.y = (acc[t][1] - mu)*rs*g.y + be.y;
            o.z = (acc[t][2] - mu)*rs*g.z + be.z;
            o.w = (acc[t][3] - mu)*rs*g.w + be.w;
            *(float4*)(hp + t*16 + quad*4) = o;
        }
    }
}

extern "C" void kernel_launch(void* const* d_in, const int* in_sizes, int n_in,
                              void* d_out, int out_size, void* d_ws, size_t ws_size,
                              hipStream_t stream) {
    const float* X     = (const float*)d_in[0];
    const float* M     = (const float*)d_in[1];
    const float* w_env = (const float*)d_in[2];
    const float* w_bur = (const float*)d_in[3];
    const float* syn   = (const float*)d_in[4];
    const float* wdw   = (const float*)d_in[5];
    const float* wpw   = (const float*)d_in[6];
    const float* wproj = (const float*)d_in[7];
    const float* gam   = (const float*)d_in[8];
    const float* bet   = (const float*)d_in[9];

    float* h      = (float*)d_out;                       // (64,2000,160)
    float* mpatch = h + (size_t)64*2000*160;             // (64,2000)

    __hip_bfloat16* wbf = (__hip_bfloat16*)d_ws;                          // [0, 40960)
    float* wn_g = (float*)((char*)d_ws + 40960);                          // 16 floats
    float* sm_g = (float*)((char*)d_ws + 41024);                          // 64 floats
    __hip_bfloat16* xsb = (__hip_bfloat16*)((char*)d_ws + 65536);         // 32.8 MB

    k_cvtw<<<80, 256, 0, stream>>>(wproj, syn, wbf, wn_g, sm_g);
    k_pre<<<3200, 256, 0, stream>>>(X, M, w_env, w_bur, wdw, wpw, wn_g, sm_g, xsb, mpatch);
    k_proj<<<1000, 256, 0, stream>>>(wbf, xsb, gam, bet, h);
}

// Round 8
// 262.677 us; speedup vs baseline: 1.1775x; 1.1775x over previous
//
#include <hip/hip_runtime.h>
#include <hip/hip_bf16.h>
#include <cstddef>

#define T_LEN 50000

typedef __attribute__((ext_vector_type(8))) short bf16x8;
typedef __attribute__((ext_vector_type(4))) float f32x4;

__device__ __forceinline__ float sp_(float x){ return (x > 20.f) ? x : log1pf(expf(x)); }
__device__ __forceinline__ float gelu1(float x){ return 0.5f*x*(1.f + erff(x*0.7071067811865475f)); }

// ---------------- kernel 0: w_proj [160][100] fp32 -> wbf [160][128] bf16 (K zero-padded) ----
__global__ void k_cvtw(const float* __restrict__ wproj, __hip_bfloat16* __restrict__ wbf)
{
    int idx = blockIdx.x*256 + threadIdx.x;
    if (idx < 160*128) {
        int d = idx >> 7, i = idx & 127;
        float v = (i < 100) ? wproj[d*100 + i] : 0.f;
        wbf[idx] = __float2bfloat16(v);
    }
}

// ---------------- kernel 1: preprocessing chain -> xs bf16 [patch][128] + m_patch ----------
// R2 per-thread code (J=4, identical FMA order), re-tiled: 500-t tile, 128 threads (2 waves).
// LDS: xb 10624 + s1b 9152 + maskb 532 + WnL 64 + SmLUT 256 + abf 5120 = ~25.7 KB
//   -> up to 6 blocks/CU (12 waves/CU). grid = 64*100 = 6400 blocks.
__global__ __launch_bounds__(128) void k_pre(
    const float* __restrict__ X, const float* __restrict__ Mq,
    const float* __restrict__ w_env, const float* __restrict__ w_bur,
    const float* __restrict__ syn, const float* __restrict__ wdw,
    const float* __restrict__ wpw,
    __hip_bfloat16* __restrict__ xs_out, float* __restrict__ mpatch)
{
    __shared__ float4 xb[664];     // x tile, t in [t0-16, t0+516), +1-per-4 padded (532 entries)
    __shared__ float4 s1b[572];    // S1 tile, t in [t0-4, t0+504), +1-per-8 padded (508 entries)
    __shared__ unsigned char maskb[532];
    __shared__ float WnL[16];
    __shared__ float4 SmLUT[16];
    __shared__ __align__(16) __hip_bfloat16 abf[20*128];  // A-layout tile: [patch][i=m*25+k]

    const int tid  = threadIdx.x;
    const int b    = blockIdx.x / 100;
    const int tile = blockIdx.x % 100;
    const int t0   = tile * 500;

    // ---- phase 1: load x = X*M (float4 over channels), build mask; zero abf K-pad ----
    const float4* X4 = (const float4*)X + (size_t)b * T_LEN;
    const float4* M4 = (const float4*)Mq + (size_t)b * T_LEN;
    #pragma unroll
    for (int jj = 0; jj < 5; ++jj) {
        int idx = tid + jj*128;
        if (idx < 532) {
            int t = t0 - 16 + idx;
            float4 xv = make_float4(0.f,0.f,0.f,0.f);
            unsigned mk = 0u;
            if (t >= 0 && t < T_LEN) {
                float4 a = X4[t], m = M4[t];
                xv = make_float4(a.x*m.x, a.y*m.y, a.z*m.z, a.w*m.w);
                mk = (m.x>0.f?1u:0u) | (m.y>0.f?2u:0u) | (m.z>0.f?4u:0u) | (m.w>0.f?8u:0u);
            }
            xb[idx + (idx>>2)] = xv;
            maskb[idx] = (unsigned char)mk;
        }
    }
    for (int idx = tid; idx < 20*28; idx += 128) {   // zero i in [100,128)
        int p = idx / 28, i = 100 + idx % 28;
        abf[p*128 + i] = __float2bfloat16(0.f);
    }
    if (tid < 4) {
        float w0 = sp_(syn[tid*4+0]), w1 = sp_(syn[tid*4+1]);
        float w2 = sp_(syn[tid*4+2]), w3 = sp_(syn[tid*4+3]);
        float inv = 1.f / fmaxf(w0+w1+w2+w3, 1e-6f);
        WnL[tid*4+0]=w0*inv; WnL[tid*4+1]=w1*inv; WnL[tid*4+2]=w2*inv; WnL[tid*4+3]=w3*inv;
    }
    __syncthreads();
    if (tid < 16) {
        float sm[4];
        #pragma unroll
        for (int m=0;m<4;++m) {
            float a = 0.f;
            #pragma unroll
            for (int c=0;c<4;++c) if (tid & (1<<c)) a += WnL[m*4+c];
            sm[m] = fminf(a, 1.f);
        }
        SmLUT[tid] = make_float4(sm[0],sm[1],sm[2],sm[3]);
    }

    // ---- phase 2: env/burst/xm -> S1 for t in [t0-4, t0+504), J=4 per thread ----
    if (tid < 127) {
        float4 env[4], bur[4], xk[4];
        #pragma unroll
        for (int j=0;j<4;++j){ env[j]=make_float4(0,0,0,0); bur[j]=make_float4(0,0,0,0); }
        float4 xprev = make_float4(0,0,0,0);
        const int base  = 4*tid;
        const int gbase = t0 - 4 + 4*tid;
        #pragma unroll
        for (int s = -12; s <= 15; ++s) {
            int lt = base + (s+12);
            float4 xc = xb[lt + (lt>>2)];
            float4 ax = make_float4(fabsf(xc.x),fabsf(xc.y),fabsf(xc.z),fabsf(xc.w));
            if (s >= -4 && s <= 7) {
                int g = gbase + s;
                float4 dx;
                if (g <= 0 || g >= T_LEN) dx = make_float4(0,0,0,0);
                else dx = make_float4(xc.x-xprev.x, xc.y-xprev.y, xc.z-xprev.z, xc.w-xprev.w);
                float4 adx = make_float4(fabsf(dx.x),fabsf(dx.y),fabsf(dx.z),fabsf(dx.w));
                #pragma unroll
                for (int j=0;j<4;++j) {
                    int bk = s + 4 - j;
                    if (bk >= 0 && bk < 9) {
                        float b0=w_bur[bk], b1=w_bur[9+bk], b2=w_bur[18+bk], b3=w_bur[27+bk];
                        bur[j].x = fmaf(b0, adx.x, bur[j].x);
                        bur[j].y = fmaf(b1, adx.y, bur[j].y);
                        bur[j].z = fmaf(b2, adx.z, bur[j].z);
                        bur[j].w = fmaf(b3, adx.w, bur[j].w);
                    }
                }
            }
            #pragma unroll
            for (int j=0;j<4;++j) {
                int k = s + 12 - j;
                if (k >= 0 && k < 25) {
                    float e0=w_env[k], e1=w_env[25+k], e2=w_env[50+k], e3=w_env[75+k];
                    env[j].x = fmaf(e0, ax.x, env[j].x);
                    env[j].y = fmaf(e1, ax.y, env[j].y);
                    env[j].z = fmaf(e2, ax.z, env[j].z);
                    env[j].w = fmaf(e3, ax.w, env[j].w);
                }
            }
            if (s >= 0 && s <= 3) xk[s] = xc;
            xprev = xc;
        }
        #pragma unroll
        for (int j=0;j<4;++j) {
            int g = gbase + j;
            float4 xm = make_float4(
                0.9f*env[j].x + 0.6f*bur[j].x + 0.2f*xk[j].x,
                0.9f*env[j].y + 0.6f*bur[j].y + 0.2f*xk[j].y,
                0.9f*env[j].z + 0.6f*bur[j].z + 0.2f*xk[j].z,
                0.9f*env[j].w + 0.6f*bur[j].w + 0.2f*xk[j].w);
            float4 out = make_float4(0,0,0,0);
            if (g >= 0 && g < T_LEN) {
                out.x = WnL[0]*xm.x  + WnL[1]*xm.y  + WnL[2]*xm.z  + WnL[3]*xm.w;
                out.y = WnL[4]*xm.x  + WnL[5]*xm.y  + WnL[6]*xm.z  + WnL[7]*xm.w;
                out.z = WnL[8]*xm.x  + WnL[9]*xm.y  + WnL[10]*xm.z + WnL[11]*xm.w;
                out.w = WnL[12]*xm.x + WnL[13]*xm.y + WnL[14]*xm.z + WnL[15]*xm.w;
            }
            int ls = base + j;
            s1b[ls + (ls>>3)] = out;
        }
    }
    __syncthreads();

    // ---- phase 3: pre-dw + gelu + pw + gelu, * Sm -> abf (bf16, A-layout) ----
    if (tid < 125) {
        float4 s2a[4];
        #pragma unroll
        for (int j=0;j<4;++j) s2a[j]=make_float4(0,0,0,0);
        const int base = 4*tid;
        #pragma unroll
        for (int s = -4; s <= 7; ++s) {
            int ls = base + s + 4;
            float4 sc = s1b[ls + (ls>>3)];
            #pragma unroll
            for (int j=0;j<4;++j) {
                int k = s + 4 - j;
                if (k >= 0 && k < 9) {
                    float d0=wdw[k], d1=wdw[9+k], d2=wdw[18+k], d3=wdw[27+k];
                    s2a[j].x = fmaf(d0, sc.x, s2a[j].x);
                    s2a[j].y = fmaf(d1, sc.y, s2a[j].y);
                    s2a[j].z = fmaf(d2, sc.z, s2a[j].z);
                    s2a[j].w = fmaf(d3, sc.w, s2a[j].w);
                }
            }
        }
        #pragma unroll
        for (int j=0;j<4;++j) {
            int t = base + j;              // local t in [0,500)
            float g0 = gelu1(s2a[j].x), g1 = gelu1(s2a[j].y);
            float g2 = gelu1(s2a[j].z), g3 = gelu1(s2a[j].w);
            float4 sm = SmLUT[maskb[t + 16]];
            int p = t / 25, k = t % 25;
            float smv[4] = {sm.x, sm.y, sm.z, sm.w};
            #pragma unroll
            for (int o=0;o<4;++o) {
                float v = wpw[o*4+0]*g0 + wpw[o*4+1]*g1 + wpw[o*4+2]*g2 + wpw[o*4+3]*g3;
                abf[p*128 + o*25 + k] = __float2bfloat16(gelu1(v) * smv[o]);
            }
        }
    }
    __syncthreads();

    // ---- phase 4: copy abf -> global (coalesced), m_patch from mask bits ----
    {
        const float4* src = (const float4*)abf;
        float4* dst = (float4*)(xs_out + (size_t)(b*2000 + tile*20)*128);
        #pragma unroll
        for (int it = 0; it < 3; ++it) {
            int idx = tid + it*128;
            if (idx < 320) dst[idx] = src[idx];
        }
    }
    // softplus > 0 strictly => all normalized W entries > 0 => sum_m Sm[t] > 0 <=> mask[t] != 0
    if (tid < 20) {
        int cnt = 0;
        #pragma unroll
        for (int k=0;k<25;++k) cnt += (maskb[16 + tid*25 + k] != 0) ? 1 : 0;
        mpatch[(size_t)b*2000 + tile*20 + tid] = (cnt >= 3) ? 1.f : 0.f;
    }
}

// ---------------- kernel 2: MFMA patch projection (M=128000, N=160, K=128) + LayerNorm ----
// R2-verified version, byte-identical. Operand-swapped MFMA; float4 stores.
__global__ __launch_bounds__(256) void k_proj(
    const __hip_bfloat16* __restrict__ wbf, const __hip_bfloat16* __restrict__ xsg,
    const float* __restrict__ gamma, const float* __restrict__ beta,
    float* __restrict__ hout)
{
    __shared__ __align__(16) unsigned short Wl[160*136];  // [d][K=128 pad 136]
    __shared__ __align__(16) unsigned short Al[64*136];   // [patch][K=128 pad 136]
    const int tid  = threadIdx.x;
    const int wv   = tid >> 6, lane = tid & 63;
    const int n    = lane & 15, quad = lane >> 4;

    {
        const float4* wg = (const float4*)wbf;
        #pragma unroll
        for (int it = 0; it < 10; ++it) {
            int idx = tid + it*256;
            int row = idx >> 4, cir = idx & 15;
            *(float4*)(Wl + row*136 + cir*8) = wg[idx];
        }
    }

    for (int bt = 0; bt < 2; ++bt) {
        const int p0 = (blockIdx.x*2 + bt) * 64;
        __syncthreads();   // covers Wl visibility at bt=0; Al reuse at bt=1
        {
            const float4* ag = (const float4*)(xsg + (size_t)p0*128);
            #pragma unroll
            for (int it = 0; it < 4; ++it) {
                int idx = tid + it*256;
                int row = idx >> 4, cir = idx & 15;
                *(float4*)(Al + row*136 + cir*8) = ag[idx];
            }
        }
        __syncthreads();

        f32x4 acc[10];
        #pragma unroll
        for (int t = 0; t < 10; ++t) acc[t] = (f32x4){0.f,0.f,0.f,0.f};
        #pragma unroll
        for (int kk = 0; kk < 4; ++kk) {
            bf16x8 pf = *(const bf16x8*)(Al + (wv*16 + n)*136 + kk*32 + quad*8);  // patch frag (B)
            #pragma unroll
            for (int t = 0; t < 10; ++t) {
                bf16x8 wf = *(const bf16x8*)(Wl + (t*16 + n)*136 + kk*32 + quad*8); // W frag (A)
                acc[t] = __builtin_amdgcn_mfma_f32_16x16x32_bf16(wf, pf, acc[t], 0, 0, 0);
            }
        }

        float s = 0.f;
        #pragma unroll
        for (int t = 0; t < 10; ++t) {
            #pragma unroll
            for (int r = 0; r < 4; ++r) s += acc[t][r];
        }
        s += __shfl_xor(s, 16, 64); s += __shfl_xor(s, 32, 64);
        const float mu = s * (1.f/160.f);
        float q = 0.f;
        #pragma unroll
        for (int t = 0; t < 10; ++t) {
            #pragma unroll
            for (int r = 0; r < 4; ++r) { float dv = acc[t][r] - mu; q = fmaf(dv, dv, q); }
        }
        q += __shfl_xor(q, 16, 64); q += __shfl_xor(q, 32, 64);
        const float rs = rsqrtf(q * (1.f/160.f) + 1e-5f);

        const int prow = p0 + wv*16 + n;
        float* hp = hout + (size_t)prow*160;
        #pragma unroll
        for (int t = 0; t < 10; ++t) {
            const float4 g  = *(const float4*)(gamma + t*16 + quad*4);
            const float4 be = *(const float4*)(beta  + t*16 + quad*4);
            float4 o;
            o.x = (acc[t][0] - mu)*rs*g.x + be.x;
            o.y = (acc[t][1] - mu)*rs*g.y + be.y;
            o.z = (acc[t][2] - mu)*rs*g.z + be.z;
            o.w = (acc[t][3] - mu)*rs*g.w + be.w;
            *(float4*)(hp + t*16 + quad*4) = o;
        }
    }
}

extern "C" void kernel_launch(void* const* d_in, const int* in_sizes, int n_in,
                              void* d_out, int out_size, void* d_ws, size_t ws_size,
                              hipStream_t stream) {
    const float* X     = (const float*)d_in[0];
    const float* M     = (const float*)d_in[1];
    const float* w_env = (const float*)d_in[2];
    const float* w_bur = (const float*)d_in[3];
    const float* syn   = (const float*)d_in[4];
    const float* wdw   = (const float*)d_in[5];
    const float* wpw   = (const float*)d_in[6];
    const float* wproj = (const float*)d_in[7];
    const float* gam   = (const float*)d_in[8];
    const float* bet   = (const float*)d_in[9];

    float* h      = (float*)d_out;                       // (64,2000,160)
    float* mpatch = h + (size_t)64*2000*160;             // (64,2000)

    __hip_bfloat16* wbf = (__hip_bfloat16*)d_ws;                          // 40 KB
    __hip_bfloat16* xsb = (__hip_bfloat16*)((char*)d_ws + 65536);         // 128000*128*2 = 32.8 MB

    k_cvtw<<<80, 256, 0, stream>>>(wproj, wbf);
    k_pre<<<6400, 128, 0, stream>>>(X, M, w_env, w_bur, syn, wdw, wpw, xsb, mpatch);
    k_proj<<<1000, 256, 0, stream>>>(wbf, xsb, gam, bet, h);
}

// Round 10
// 248.125 us; speedup vs baseline: 1.2465x; 1.0586x over previous
//
#include <hip/hip_runtime.h>
#include <hip/hip_bf16.h>
#include <cstddef>

#define T_LEN 50000

typedef __attribute__((ext_vector_type(8))) short bf16x8;
typedef __attribute__((ext_vector_type(4))) float f32x4;

__device__ __forceinline__ float sp_(float x){ return (x > 20.f) ? x : log1pf(expf(x)); }
__device__ __forceinline__ float gelu1(float x){ return 0.5f*x*(1.f + erff(x*0.7071067811865475f)); }
__device__ __forceinline__ unsigned short f2bf(float x){
    __hip_bfloat16 h = __float2bfloat16(x);
    return *reinterpret_cast<unsigned short*>(&h);
}

// ---------------- kernel 0: wbf convert + Toeplitz A-matrices for conv-MFMA ----------------
// ag layout: [12][16][32] bf16. m = ty*4+ch: ty0 = env chunk1 (A[i][j]=e[j-i], k in [0,24]),
// ty1 = env chunk2 (A[i][j]=e[j+32-i]), ty2 = burst (A[i][j]=b[j-i-8], k in [0,8]).
__global__ void k_cvtw(const float* __restrict__ wproj, const float* __restrict__ w_env,
                       const float* __restrict__ w_bur,
                       __hip_bfloat16* __restrict__ wbf, __hip_bfloat16* __restrict__ ag)
{
    int gid = blockIdx.x*256 + threadIdx.x;
    if (gid < 160*128) {
        int d = gid >> 7, i = gid & 127;
        float v = (i < 100) ? wproj[d*100 + i] : 0.f;
        wbf[gid] = __float2bfloat16(v);
    }
    int idx2 = gid - 160*128;
    if (idx2 >= 0 && idx2 < 12*512) {
        int m = idx2 >> 9, rem = idx2 & 511, i = rem >> 5, j = rem & 31;
        int ch = m & 3, ty = m >> 2;
        float v = 0.f;
        if (ty == 0)      { int k = j - i;      if (k >= 0 && k <= 24) v = w_env[ch*25 + k]; }
        else if (ty == 1) { int k = j + 32 - i; if (k <= 24)           v = w_env[ch*25 + k]; }
        else              { int k = j - i - 8;  if (k >= 0 && k <= 8)  v = w_bur[ch*9  + k]; }
        ag[idx2] = __float2bfloat16(v);
    }
}

// ---------------- kernel 1: preprocessing chain -> xs bf16 [patch][128] + m_patch ----------
// Phase 2 env/burst convs on the MATRIX pipe: per wave, 16 tiles x 16 offsets per channel
// via 3 MFMAs (Toeplitz A x windowed-signal B). Synergy/blend fp32 in epilogue.
// Phase 3/4 identical to the R2-verified kernel. 256 threads, 1000-t tile, grid 3200.
// R9 NaN fix: stage the FULL [0,1088) bf16 planes (chunk-2 B-frags read up to idx 1071;
// 0 x uninitialized-NaN = NaN poisoned the MFMA accumulator). mask4 enlarged 262 -> 272.
__global__ __launch_bounds__(256) void k_pre(
    const float* __restrict__ X, const float* __restrict__ Mq,
    const float* __restrict__ syn, const float* __restrict__ wdw,
    const float* __restrict__ wpw, const __hip_bfloat16* __restrict__ ag,
    __hip_bfloat16* __restrict__ xs_out, float* __restrict__ mpatch)
{
    __shared__ float4 xb[1152];          // x (fp32), u in [0,1024) = t0-4+u, pad +1 per 8
    __shared__ float4 s1b[1134];         // S1, u in [0,1008), pad +1 per 8
    __shared__ unsigned int mask4[272];  // mask bytes, idx = t - (t0-16); [262..272) pad
    __shared__ float WnL[16];
    __shared__ float4 SmLUT[16];
    __shared__ __align__(16) unsigned char upool[17408];
    unsigned short* axb  = (unsigned short*)upool;   // [4][1088] bf16 |x|,  idx-indexed
    unsigned short* adxb = axb + 4*1088;             // [4][1088] bf16 |dx|, idx-indexed
    __hip_bfloat16* abf  = (__hip_bfloat16*)upool;   // phase 3+: [40][128]

    const int tid  = threadIdx.x;
    const int b    = blockIdx.x / 50;
    const int tile = blockIdx.x % 50;
    const int t0   = tile * 1000;
    unsigned char* maskb = (unsigned char*)mask4;

    const float4* X4 = (const float4*)X + (size_t)b * T_LEN;
    const float4* M4 = (const float4*)Mq + (size_t)b * T_LEN;

    // ---- phase 1: x=X*M fp32 -> xb ; |x|,|dx| bf16 -> planes (FULL 1088) ; mask bytes ----
    for (int g0 = tid*4; g0 < 1088; g0 += 1024) {
        float4 xv[5];                    // x at idx g0-1 .. g0+3
        unsigned mk = 0u;
        #pragma unroll
        for (int e = 0; e < 5; ++e) {
            int t = t0 - 17 + g0 + e;
            float4 x = make_float4(0.f,0.f,0.f,0.f);
            if (t >= 0 && t < T_LEN) {
                float4 a = X4[t], m = M4[t];
                x = make_float4(a.x*m.x, a.y*m.y, a.z*m.z, a.w*m.w);
                if (e >= 1) {
                    unsigned mb = (m.x>0.f?1u:0u)|(m.y>0.f?2u:0u)|(m.z>0.f?4u:0u)|(m.w>0.f?8u:0u);
                    mk |= mb << ((e-1)*8);
                }
            }
            xv[e] = x;
        }
        mask4[g0>>2] = mk;
        #pragma unroll
        for (int e = 1; e < 5; ++e) {
            int u = g0 + e - 13;         // u = idx - 12
            if (u >= 0 && u < 1024) xb[u + (u>>3)] = xv[e];
        }
        unsigned short ua[4][4], ud[4][4];
        #pragma unroll
        for (int e = 1; e < 5; ++e) {
            int gt = t0 - 16 + g0 + (e-1);
            float4 x = xv[e], xp = xv[e-1];
            bool dv = (gt >= 1 && gt < T_LEN);
            float d0 = dv ? x.x - xp.x : 0.f, d1 = dv ? x.y - xp.y : 0.f;
            float d2 = dv ? x.z - xp.z : 0.f, d3 = dv ? x.w - xp.w : 0.f;
            ua[0][e-1] = f2bf(fabsf(x.x)); ua[1][e-1] = f2bf(fabsf(x.y));
            ua[2][e-1] = f2bf(fabsf(x.z)); ua[3][e-1] = f2bf(fabsf(x.w));
            ud[0][e-1] = f2bf(fabsf(d0));  ud[1][e-1] = f2bf(fabsf(d1));
            ud[2][e-1] = f2bf(fabsf(d2));  ud[3][e-1] = f2bf(fabsf(d3));
        }
        #pragma unroll
        for (int c = 0; c < 4; ++c) {
            *(ushort4*)(axb  + c*1088 + g0) = make_ushort4(ua[c][0],ua[c][1],ua[c][2],ua[c][3]);
            *(ushort4*)(adxb + c*1088 + g0) = make_ushort4(ud[c][0],ud[c][1],ud[c][2],ud[c][3]);
        }
    }
    if (tid < 4) {
        float w0 = sp_(syn[tid*4+0]), w1 = sp_(syn[tid*4+1]);
        float w2 = sp_(syn[tid*4+2]), w3 = sp_(syn[tid*4+3]);
        float inv = 1.f / fmaxf(w0+w1+w2+w3, 1e-6f);
        WnL[tid*4+0]=w0*inv; WnL[tid*4+1]=w1*inv; WnL[tid*4+2]=w2*inv; WnL[tid*4+3]=w3*inv;
    }
    __syncthreads();
    if (tid < 16) {
        float sm[4];
        #pragma unroll
        for (int m=0;m<4;++m) {
            float a = 0.f;
            #pragma unroll
            for (int c=0;c<4;++c) if (tid & (1<<c)) a += WnL[m*4+c];
            sm[m] = fminf(a, 1.f);
        }
        SmLUT[tid] = make_float4(sm[0],sm[1],sm[2],sm[3]);
    }

    // ---- phase 2: env/burst via MFMA, then fp32 blend + synergy -> s1b ----
    {
        const int lane = tid & 63, wv = tid >> 6;
        const int n = lane & 15, q = lane >> 4;
        bf16x8 A1[4], A2[4], Ab[4];
        #pragma unroll
        for (int c = 0; c < 4; ++c) {
            A1[c] = *(const bf16x8*)(ag + (c   )*512 + n*32 + q*8);
            A2[c] = *(const bf16x8*)(ag + (4+c )*512 + n*32 + q*8);
            Ab[c] = *(const bf16x8*)(ag + (8+c )*512 + n*32 + q*8);
        }
        const int jb = 256*wv + 16*n;
        f32x4 ea[4], ba[4];
        #pragma unroll
        for (int c = 0; c < 4; ++c) {
            bf16x8 B1 = *(const bf16x8*)(axb  + c*1088 + jb      + q*8);
            bf16x8 B2 = *(const bf16x8*)(axb  + c*1088 + jb + 32 + q*8);
            bf16x8 Bb = *(const bf16x8*)(adxb + c*1088 + jb      + q*8);
            f32x4 z = (f32x4){0.f,0.f,0.f,0.f};
            z     = __builtin_amdgcn_mfma_f32_16x16x32_bf16(A1[c], B1, z, 0, 0, 0);
            ea[c] = __builtin_amdgcn_mfma_f32_16x16x32_bf16(A2[c], B2, z, 0, 0, 0);
            ba[c] = __builtin_amdgcn_mfma_f32_16x16x32_bf16(Ab[c], Bb, (f32x4){0.f,0.f,0.f,0.f}, 0, 0, 0);
        }
        #pragma unroll
        for (int r = 0; r < 4; ++r) {
            const int u = 256*wv + 16*n + 4*q + r;   // D: row 4q+r, col n
            if (u < 1008) {
                const int g = t0 - 4 + u;
                float4 out = make_float4(0.f,0.f,0.f,0.f);
                if (g >= 0 && g < T_LEN) {
                    float4 x = xb[u + (u>>3)];
                    float m0 = 0.9f*ea[0][r] + 0.6f*ba[0][r] + 0.2f*x.x;
                    float m1 = 0.9f*ea[1][r] + 0.6f*ba[1][r] + 0.2f*x.y;
                    float m2 = 0.9f*ea[2][r] + 0.6f*ba[2][r] + 0.2f*x.z;
                    float m3 = 0.9f*ea[3][r] + 0.6f*ba[3][r] + 0.2f*x.w;
                    out.x = WnL[0]*m0  + WnL[1]*m1  + WnL[2]*m2  + WnL[3]*m3;
                    out.y = WnL[4]*m0  + WnL[5]*m1  + WnL[6]*m2  + WnL[7]*m3;
                    out.z = WnL[8]*m0  + WnL[9]*m1  + WnL[10]*m2 + WnL[11]*m3;
                    out.w = WnL[12]*m0 + WnL[13]*m1 + WnL[14]*m2 + WnL[15]*m3;
                }
                s1b[u + (u>>3)] = out;
            }
        }
    }
    __syncthreads();   // upool now becomes abf

    // ---- phase 3: pre-dw + gelu + pw + gelu, * Sm -> abf (identical math to R2) ----
    for (int idx = tid; idx < 40*28; idx += 256) {   // zero abf K-pad i in [100,128)
        int p = idx / 28, i = 100 + idx % 28;
        abf[p*128 + i] = __float2bfloat16(0.f);
    }
    if (tid < 250) {
        float4 s2a[4];
        #pragma unroll
        for (int j=0;j<4;++j) s2a[j]=make_float4(0.f,0.f,0.f,0.f);
        const int base = 4*tid;
        #pragma unroll
        for (int s = -4; s <= 7; ++s) {
            int ls = base + s + 4;
            float4 sc = s1b[ls + (ls>>3)];
            #pragma unroll
            for (int j=0;j<4;++j) {
                int k = s + 4 - j;
                if (k >= 0 && k < 9) {
                    float d0=wdw[k], d1=wdw[9+k], d2=wdw[18+k], d3=wdw[27+k];
                    s2a[j].x = fmaf(d0, sc.x, s2a[j].x);
                    s2a[j].y = fmaf(d1, sc.y, s2a[j].y);
                    s2a[j].z = fmaf(d2, sc.z, s2a[j].z);
                    s2a[j].w = fmaf(d3, sc.w, s2a[j].w);
                }
            }
        }
        #pragma unroll
        for (int j=0;j<4;++j) {
            int t = base + j;              // local t in [0,1000)
            float g0 = gelu1(s2a[j].x), g1 = gelu1(s2a[j].y);
            float g2 = gelu1(s2a[j].z), g3 = gelu1(s2a[j].w);
            float4 sm = SmLUT[maskb[t + 16]];
            int p = t / 25, k = t % 25;
            float smv[4] = {sm.x, sm.y, sm.z, sm.w};
            #pragma unroll
            for (int o=0;o<4;++o) {
                float v = wpw[o*4+0]*g0 + wpw[o*4+1]*g1 + wpw[o*4+2]*g2 + wpw[o*4+3]*g3;
                abf[p*128 + o*25 + k] = __float2bfloat16(gelu1(v) * smv[o]);
            }
        }
    }
    __syncthreads();

    // ---- phase 4: copy abf -> global (coalesced), m_patch from mask bits ----
    {
        const float4* src = (const float4*)abf;
        float4* dst = (float4*)(xs_out + (size_t)(b*2000 + tile*40)*128);
        #pragma unroll
        for (int it = 0; it < 3; ++it) {
            int idx = tid + it*256;
            if (idx < 640) dst[idx] = src[idx];
        }
    }
    if (tid < 40) {
        int cnt = 0;
        #pragma unroll
        for (int k=0;k<25;++k) cnt += (maskb[16 + tid*25 + k] != 0) ? 1 : 0;
        mpatch[(size_t)b*2000 + tile*40 + tid] = (cnt >= 3) ? 1.f : 0.f;
    }
}

// ---------------- kernel 2: MFMA patch projection (M=128000, N=160, K=128) + LayerNorm ----
// R2-verified version, byte-identical. Operand-swapped MFMA; float4 stores.
__global__ __launch_bounds__(256) void k_proj(
    const __hip_bfloat16* __restrict__ wbf, const __hip_bfloat16* __restrict__ xsg,
    const float* __restrict__ gamma, const float* __restrict__ beta,
    float* __restrict__ hout)
{
    __shared__ __align__(16) unsigned short Wl[160*136];
    __shared__ __align__(16) unsigned short Al[64*136];
    const int tid  = threadIdx.x;
    const int wv   = tid >> 6, lane = tid & 63;
    const int n    = lane & 15, quad = lane >> 4;

    {
        const float4* wg = (const float4*)wbf;
        #pragma unroll
        for (int it = 0; it < 10; ++it) {
            int idx = tid + it*256;
            int row = idx >> 4, cir = idx & 15;
            *(float4*)(Wl + row*136 + cir*8) = wg[idx];
        }
    }

    for (int bt = 0; bt < 2; ++bt) {
        const int p0 = (blockIdx.x*2 + bt) * 64;
        __syncthreads();
        {
            const float4* ag2 = (const float4*)(xsg + (size_t)p0*128);
            #pragma unroll
            for (int it = 0; it < 4; ++it) {
                int idx = tid + it*256;
                int row = idx >> 4, cir = idx & 15;
                *(float4*)(Al + row*136 + cir*8) = ag2[idx];
            }
        }
        __syncthreads();

        f32x4 acc[10];
        #pragma unroll
        for (int t = 0; t < 10; ++t) acc[t] = (f32x4){0.f,0.f,0.f,0.f};
        #pragma unroll
        for (int kk = 0; kk < 4; ++kk) {
            bf16x8 pf = *(const bf16x8*)(Al + (wv*16 + n)*136 + kk*32 + quad*8);
            #pragma unroll
            for (int t = 0; t < 10; ++t) {
                bf16x8 wf = *(const bf16x8*)(Wl + (t*16 + n)*136 + kk*32 + quad*8);
                acc[t] = __builtin_amdgcn_mfma_f32_16x16x32_bf16(wf, pf, acc[t], 0, 0, 0);
            }
        }

        float s = 0.f;
        #pragma unroll
        for (int t = 0; t < 10; ++t) {
            #pragma unroll
            for (int r = 0; r < 4; ++r) s += acc[t][r];
        }
        s += __shfl_xor(s, 16, 64); s += __shfl_xor(s, 32, 64);
        const float mu = s * (1.f/160.f);
        float q = 0.f;
        #pragma unroll
        for (int t = 0; t < 10; ++t) {
            #pragma unroll
            for (int r = 0; r < 4; ++r) { float dv = acc[t][r] - mu; q = fmaf(dv, dv, q); }
        }
        q += __shfl_xor(q, 16, 64); q += __shfl_xor(q, 32, 64);
        const float rs = rsqrtf(q * (1.f/160.f) + 1e-5f);

        const int prow = p0 + wv*16 + n;
        float* hp = hout + (size_t)prow*160;
        #pragma unroll
        for (int t = 0; t < 10; ++t) {
            const float4 g  = *(const float4*)(gamma + t*16 + quad*4);
            const float4 be = *(const float4*)(beta  + t*16 + quad*4);
            float4 o;
            o.x = (acc[t][0] - mu)*rs*g.x + be.x;
            o.y = (acc[t][1] - mu)*rs*g.y + be.y;
            o.z = (acc[t][2] - mu)*rs*g.z + be.z;
            o.w = (acc[t][3] - mu)*rs*g.w + be.w;
            *(float4*)(hp + t*16 + quad*4) = o;
        }
    }
}

extern "C" void kernel_launch(void* const* d_in, const int* in_sizes, int n_in,
                              void* d_out, int out_size, void* d_ws, size_t ws_size,
                              hipStream_t stream) {
    const float* X     = (const float*)d_in[0];
    const float* M     = (const float*)d_in[1];
    const float* w_env = (const float*)d_in[2];
    const float* w_bur = (const float*)d_in[3];
    const float* syn   = (const float*)d_in[4];
    const float* wdw   = (const float*)d_in[5];
    const float* wpw   = (const float*)d_in[6];
    const float* wproj = (const float*)d_in[7];
    const float* gam   = (const float*)d_in[8];
    const float* bet   = (const float*)d_in[9];

    float* h      = (float*)d_out;                       // (64,2000,160)
    float* mpatch = h + (size_t)64*2000*160;             // (64,2000)

    __hip_bfloat16* wbf = (__hip_bfloat16*)d_ws;                          // [0, 40960)
    __hip_bfloat16* agm = (__hip_bfloat16*)((char*)d_ws + 40960);         // 12 KB Toeplitz A
    __hip_bfloat16* xsb = (__hip_bfloat16*)((char*)d_ws + 65536);         // 32.8 MB

    k_cvtw<<<104, 256, 0, stream>>>(wproj, w_env, w_bur, wbf, agm);
    k_pre<<<3200, 256, 0, stream>>>(X, M, syn, wdw, wpw, agm, xsb, mpatch);
    k_proj<<<1000, 256, 0, stream>>>(wbf, xsb, gam, bet, h);
}

// Round 11
// 243.729 us; speedup vs baseline: 1.2690x; 1.0180x over previous
//
#include <hip/hip_runtime.h>
#include <hip/hip_bf16.h>
#include <cstddef>

#define T_LEN 50000

typedef __attribute__((ext_vector_type(8))) short bf16x8;
typedef __attribute__((ext_vector_type(4))) float f32x4;

__device__ __forceinline__ float sp_(float x){ return (x > 20.f) ? x : log1pf(expf(x)); }
__device__ __forceinline__ float gelu1(float x){ return 0.5f*x*(1.f + erff(x*0.7071067811865475f)); }
// tanh-form GELU via fast exp: max |diff vs exact| ~3e-3, ~9 ops vs ~25.
__device__ __forceinline__ float gelu_t(float x){
    float u  = 0.797884560802865f * fmaf(0.044715f*x*x, x, x);
    float e  = __expf(-2.f*fabsf(u));
    float th = (1.f - e) / (1.f + e);
    th = (u >= 0.f) ? th : -th;
    return 0.5f * x * (1.f + th);
}
__device__ __forceinline__ unsigned short f2bf(float x){
    __hip_bfloat16 h = __float2bfloat16(x);
    return *reinterpret_cast<unsigned short*>(&h);
}

// ---------------- kernel 0: wbf convert + Toeplitz A-matrices for conv-MFMA ----------------
// ag layout: [12][16][32] bf16. m = ty*4+ch: ty0 = env chunk1 (A[i][j]=e[j-i], k in [0,24]),
// ty1 = env chunk2 (A[i][j]=e[j+32-i]), ty2 = burst (A[i][j]=b[j-i-8], k in [0,8]).
__global__ void k_cvtw(const float* __restrict__ wproj, const float* __restrict__ w_env,
                       const float* __restrict__ w_bur,
                       __hip_bfloat16* __restrict__ wbf, __hip_bfloat16* __restrict__ ag)
{
    int gid = blockIdx.x*256 + threadIdx.x;
    if (gid < 160*128) {
        int d = gid >> 7, i = gid & 127;
        float v = (i < 100) ? wproj[d*100 + i] : 0.f;
        wbf[gid] = __float2bfloat16(v);
    }
    int idx2 = gid - 160*128;
    if (idx2 >= 0 && idx2 < 12*512) {
        int m = idx2 >> 9, rem = idx2 & 511, i = rem >> 5, j = rem & 31;
        int ch = m & 3, ty = m >> 2;
        float v = 0.f;
        if (ty == 0)      { int k = j - i;      if (k >= 0 && k <= 24) v = w_env[ch*25 + k]; }
        else if (ty == 1) { int k = j + 32 - i; if (k <= 24)           v = w_env[ch*25 + k]; }
        else              { int k = j - i - 8;  if (k >= 0 && k <= 8)  v = w_bur[ch*9  + k]; }
        ag[idx2] = __float2bfloat16(v);
    }
}

// ---------------- kernel 1: preprocessing chain -> xs bf16 [patch][128] + m_patch ----------
// R10-verified structure (conv on MFMA pipe). Only change: phase-3 GELUs use gelu_t.
__global__ __launch_bounds__(256) void k_pre(
    const float* __restrict__ X, const float* __restrict__ Mq,
    const float* __restrict__ syn, const float* __restrict__ wdw,
    const float* __restrict__ wpw, const __hip_bfloat16* __restrict__ ag,
    __hip_bfloat16* __restrict__ xs_out, float* __restrict__ mpatch)
{
    __shared__ float4 xb[1152];          // x (fp32), u in [0,1024) = t0-4+u, pad +1 per 8
    __shared__ float4 s1b[1134];         // S1, u in [0,1008), pad +1 per 8
    __shared__ unsigned int mask4[272];  // mask bytes, idx = t - (t0-16); [262..272) pad
    __shared__ float WnL[16];
    __shared__ float4 SmLUT[16];
    __shared__ __align__(16) unsigned char upool[17408];
    unsigned short* axb  = (unsigned short*)upool;   // [4][1088] bf16 |x|,  idx-indexed
    unsigned short* adxb = axb + 4*1088;             // [4][1088] bf16 |dx|, idx-indexed
    __hip_bfloat16* abf  = (__hip_bfloat16*)upool;   // phase 3+: [40][128]

    const int tid  = threadIdx.x;
    const int b    = blockIdx.x / 50;
    const int tile = blockIdx.x % 50;
    const int t0   = tile * 1000;
    unsigned char* maskb = (unsigned char*)mask4;

    const float4* X4 = (const float4*)X + (size_t)b * T_LEN;
    const float4* M4 = (const float4*)Mq + (size_t)b * T_LEN;

    // ---- phase 1: x=X*M fp32 -> xb ; |x|,|dx| bf16 -> planes (FULL 1088) ; mask bytes ----
    for (int g0 = tid*4; g0 < 1088; g0 += 1024) {
        float4 xv[5];                    // x at idx g0-1 .. g0+3
        unsigned mk = 0u;
        #pragma unroll
        for (int e = 0; e < 5; ++e) {
            int t = t0 - 17 + g0 + e;
            float4 x = make_float4(0.f,0.f,0.f,0.f);
            if (t >= 0 && t < T_LEN) {
                float4 a = X4[t], m = M4[t];
                x = make_float4(a.x*m.x, a.y*m.y, a.z*m.z, a.w*m.w);
                if (e >= 1) {
                    unsigned mb = (m.x>0.f?1u:0u)|(m.y>0.f?2u:0u)|(m.z>0.f?4u:0u)|(m.w>0.f?8u:0u);
                    mk |= mb << ((e-1)*8);
                }
            }
            xv[e] = x;
        }
        mask4[g0>>2] = mk;
        #pragma unroll
        for (int e = 1; e < 5; ++e) {
            int u = g0 + e - 13;         // u = idx - 12
            if (u >= 0 && u < 1024) xb[u + (u>>3)] = xv[e];
        }
        unsigned short ua[4][4], ud[4][4];
        #pragma unroll
        for (int e = 1; e < 5; ++e) {
            int gt = t0 - 16 + g0 + (e-1);
            float4 x = xv[e], xp = xv[e-1];
            bool dv = (gt >= 1 && gt < T_LEN);
            float d0 = dv ? x.x - xp.x : 0.f, d1 = dv ? x.y - xp.y : 0.f;
            float d2 = dv ? x.z - xp.z : 0.f, d3 = dv ? x.w - xp.w : 0.f;
            ua[0][e-1] = f2bf(fabsf(x.x)); ua[1][e-1] = f2bf(fabsf(x.y));
            ua[2][e-1] = f2bf(fabsf(x.z)); ua[3][e-1] = f2bf(fabsf(x.w));
            ud[0][e-1] = f2bf(fabsf(d0));  ud[1][e-1] = f2bf(fabsf(d1));
            ud[2][e-1] = f2bf(fabsf(d2));  ud[3][e-1] = f2bf(fabsf(d3));
        }
        #pragma unroll
        for (int c = 0; c < 4; ++c) {
            *(ushort4*)(axb  + c*1088 + g0) = make_ushort4(ua[c][0],ua[c][1],ua[c][2],ua[c][3]);
            *(ushort4*)(adxb + c*1088 + g0) = make_ushort4(ud[c][0],ud[c][1],ud[c][2],ud[c][3]);
        }
    }
    if (tid < 4) {
        float w0 = sp_(syn[tid*4+0]), w1 = sp_(syn[tid*4+1]);
        float w2 = sp_(syn[tid*4+2]), w3 = sp_(syn[tid*4+3]);
        float inv = 1.f / fmaxf(w0+w1+w2+w3, 1e-6f);
        WnL[tid*4+0]=w0*inv; WnL[tid*4+1]=w1*inv; WnL[tid*4+2]=w2*inv; WnL[tid*4+3]=w3*inv;
    }
    __syncthreads();
    if (tid < 16) {
        float sm[4];
        #pragma unroll
        for (int m=0;m<4;++m) {
            float a = 0.f;
            #pragma unroll
            for (int c=0;c<4;++c) if (tid & (1<<c)) a += WnL[m*4+c];
            sm[m] = fminf(a, 1.f);
        }
        SmLUT[tid] = make_float4(sm[0],sm[1],sm[2],sm[3]);
    }

    // ---- phase 2: env/burst via MFMA, then fp32 blend + synergy -> s1b ----
    {
        const int lane = tid & 63, wv = tid >> 6;
        const int n = lane & 15, q = lane >> 4;
        bf16x8 A1[4], A2[4], Ab[4];
        #pragma unroll
        for (int c = 0; c < 4; ++c) {
            A1[c] = *(const bf16x8*)(ag + (c   )*512 + n*32 + q*8);
            A2[c] = *(const bf16x8*)(ag + (4+c )*512 + n*32 + q*8);
            Ab[c] = *(const bf16x8*)(ag + (8+c )*512 + n*32 + q*8);
        }
        const int jb = 256*wv + 16*n;
        f32x4 ea[4], ba[4];
        #pragma unroll
        for (int c = 0; c < 4; ++c) {
            bf16x8 B1 = *(const bf16x8*)(axb  + c*1088 + jb      + q*8);
            bf16x8 B2 = *(const bf16x8*)(axb  + c*1088 + jb + 32 + q*8);
            bf16x8 Bb = *(const bf16x8*)(adxb + c*1088 + jb      + q*8);
            f32x4 z = (f32x4){0.f,0.f,0.f,0.f};
            z     = __builtin_amdgcn_mfma_f32_16x16x32_bf16(A1[c], B1, z, 0, 0, 0);
            ea[c] = __builtin_amdgcn_mfma_f32_16x16x32_bf16(A2[c], B2, z, 0, 0, 0);
            ba[c] = __builtin_amdgcn_mfma_f32_16x16x32_bf16(Ab[c], Bb, (f32x4){0.f,0.f,0.f,0.f}, 0, 0, 0);
        }
        #pragma unroll
        for (int r = 0; r < 4; ++r) {
            const int u = 256*wv + 16*n + 4*q + r;   // D: row 4q+r, col n
            if (u < 1008) {
                const int g = t0 - 4 + u;
                float4 out = make_float4(0.f,0.f,0.f,0.f);
                if (g >= 0 && g < T_LEN) {
                    float4 x = xb[u + (u>>3)];
                    float m0 = 0.9f*ea[0][r] + 0.6f*ba[0][r] + 0.2f*x.x;
                    float m1 = 0.9f*ea[1][r] + 0.6f*ba[1][r] + 0.2f*x.y;
                    float m2 = 0.9f*ea[2][r] + 0.6f*ba[2][r] + 0.2f*x.z;
                    float m3 = 0.9f*ea[3][r] + 0.6f*ba[3][r] + 0.2f*x.w;
                    out.x = WnL[0]*m0  + WnL[1]*m1  + WnL[2]*m2  + WnL[3]*m3;
                    out.y = WnL[4]*m0  + WnL[5]*m1  + WnL[6]*m2  + WnL[7]*m3;
                    out.z = WnL[8]*m0  + WnL[9]*m1  + WnL[10]*m2 + WnL[11]*m3;
                    out.w = WnL[12]*m0 + WnL[13]*m1 + WnL[14]*m2 + WnL[15]*m3;
                }
                s1b[u + (u>>3)] = out;
            }
        }
    }
    __syncthreads();   // upool now becomes abf

    // ---- phase 3: pre-dw + gelu_t + pw + gelu_t, * Sm -> abf ----
    for (int idx = tid; idx < 40*28; idx += 256) {   // zero abf K-pad i in [100,128)
        int p = idx / 28, i = 100 + idx % 28;
        abf[p*128 + i] = __float2bfloat16(0.f);
    }
    if (tid < 250) {
        float4 s2a[4];
        #pragma unroll
        for (int j=0;j<4;++j) s2a[j]=make_float4(0.f,0.f,0.f,0.f);
        const int base = 4*tid;
        #pragma unroll
        for (int s = -4; s <= 7; ++s) {
            int ls = base + s + 4;
            float4 sc = s1b[ls + (ls>>3)];
            #pragma unroll
            for (int j=0;j<4;++j) {
                int k = s + 4 - j;
                if (k >= 0 && k < 9) {
                    float d0=wdw[k], d1=wdw[9+k], d2=wdw[18+k], d3=wdw[27+k];
                    s2a[j].x = fmaf(d0, sc.x, s2a[j].x);
                    s2a[j].y = fmaf(d1, sc.y, s2a[j].y);
                    s2a[j].z = fmaf(d2, sc.z, s2a[j].z);
                    s2a[j].w = fmaf(d3, sc.w, s2a[j].w);
                }
            }
        }
        #pragma unroll
        for (int j=0;j<4;++j) {
            int t = base + j;              // local t in [0,1000)
            float g0 = gelu_t(s2a[j].x), g1 = gelu_t(s2a[j].y);
            float g2 = gelu_t(s2a[j].z), g3 = gelu_t(s2a[j].w);
            float4 sm = SmLUT[maskb[t + 16]];
            int p = t / 25, k = t % 25;
            float smv[4] = {sm.x, sm.y, sm.z, sm.w};
            #pragma unroll
            for (int o=0;o<4;++o) {
                float v = wpw[o*4+0]*g0 + wpw[o*4+1]*g1 + wpw[o*4+2]*g2 + wpw[o*4+3]*g3;
                abf[p*128 + o*25 + k] = __float2bfloat16(gelu_t(v) * smv[o]);
            }
        }
    }
    __syncthreads();

    // ---- phase 4: copy abf -> global (coalesced), m_patch from mask bits ----
    {
        const float4* src = (const float4*)abf;
        float4* dst = (float4*)(xs_out + (size_t)(b*2000 + tile*40)*128);
        #pragma unroll
        for (int it = 0; it < 3; ++it) {
            int idx = tid + it*256;
            if (idx < 640) dst[idx] = src[idx];
        }
    }
    if (tid < 40) {
        int cnt = 0;
        #pragma unroll
        for (int k=0;k<25;++k) cnt += (maskb[16 + tid*25 + k] != 0) ? 1 : 0;
        mpatch[(size_t)b*2000 + tile*40 + tid] = (cnt >= 3) ? 1.f : 0.f;
    }
}

// ---------------- kernel 2: MFMA patch projection (M=128000, N=160, K=128) + LayerNorm ----
// R2-verified version, byte-identical. Operand-swapped MFMA; float4 stores.
__global__ __launch_bounds__(256) void k_proj(
    const __hip_bfloat16* __restrict__ wbf, const __hip_bfloat16* __restrict__ xsg,
    const float* __restrict__ gamma, const float* __restrict__ beta,
    float* __restrict__ hout)
{
    __shared__ __align__(16) unsigned short Wl[160*136];
    __shared__ __align__(16) unsigned short Al[64*136];
    const int tid  = threadIdx.x;
    const int wv   = tid >> 6, lane = tid & 63;
    const int n    = lane & 15, quad = lane >> 4;

    {
        const float4* wg = (const float4*)wbf;
        #pragma unroll
        for (int it = 0; it < 10; ++it) {
            int idx = tid + it*256;
            int row = idx >> 4, cir = idx & 15;
            *(float4*)(Wl + row*136 + cir*8) = wg[idx];
        }
    }

    for (int bt = 0; bt < 2; ++bt) {
        const int p0 = (blockIdx.x*2 + bt) * 64;
        __syncthreads();
        {
            const float4* ag2 = (const float4*)(xsg + (size_t)p0*128);
            #pragma unroll
            for (int it = 0; it < 4; ++it) {
                int idx = tid + it*256;
                int row = idx >> 4, cir = idx & 15;
                *(float4*)(Al + row*136 + cir*8) = ag2[idx];
            }
        }
        __syncthreads();

        f32x4 acc[10];
        #pragma unroll
        for (int t = 0; t < 10; ++t) acc[t] = (f32x4){0.f,0.f,0.f,0.f};
        #pragma unroll
        for (int kk = 0; kk < 4; ++kk) {
            bf16x8 pf = *(const bf16x8*)(Al + (wv*16 + n)*136 + kk*32 + quad*8);
            #pragma unroll
            for (int t = 0; t < 10; ++t) {
                bf16x8 wf = *(const bf16x8*)(Wl + (t*16 + n)*136 + kk*32 + quad*8);
                acc[t] = __builtin_amdgcn_mfma_f32_16x16x32_bf16(wf, pf, acc[t], 0, 0, 0);
            }
        }

        float s = 0.f;
        #pragma unroll
        for (int t = 0; t < 10; ++t) {
            #pragma unroll
            for (int r = 0; r < 4; ++r) s += acc[t][r];
        }
        s += __shfl_xor(s, 16, 64); s += __shfl_xor(s, 32, 64);
        const float mu = s * (1.f/160.f);
        float q = 0.f;
        #pragma unroll
        for (int t = 0; t < 10; ++t) {
            #pragma unroll
            for (int r = 0; r < 4; ++r) { float dv = acc[t][r] - mu; q = fmaf(dv, dv, q); }
        }
        q += __shfl_xor(q, 16, 64); q += __shfl_xor(q, 32, 64);
        const float rs = rsqrtf(q * (1.f/160.f) + 1e-5f);

        const int prow = p0 + wv*16 + n;
        float* hp = hout + (size_t)prow*160;
        #pragma unroll
        for (int t = 0; t < 10; ++t) {
            const float4 g  = *(const float4*)(gamma + t*16 + quad*4);
            const float4 be = *(const float4*)(beta  + t*16 + quad*4);
            float4 o;
            o.x = (acc[t][0] - mu)*rs*g.x + be.x;
            o.y = (acc[t][1] - mu)*rs*g.y + be.y;
            o.z = (acc[t][2] - mu)*rs*g.z + be.z;
            o.w = (acc[t][3] - mu)*rs*g.w + be.w;
            *(float4*)(hp + t*16 + quad*4) = o;
        }
    }
}

extern "C" void kernel_launch(void* const* d_in, const int* in_sizes, int n_in,
                              void* d_out, int out_size, void* d_ws, size_t ws_size,
                              hipStream_t stream) {
    const float* X     = (const float*)d_in[0];
    const float* M     = (const float*)d_in[1];
    const float* w_env = (const float*)d_in[2];
    const float* w_bur = (const float*)d_in[3];
    const float* syn   = (const float*)d_in[4];
    const float* wdw   = (const float*)d_in[5];
    const float* wpw   = (const float*)d_in[6];
    const float* wproj = (const float*)d_in[7];
    const float* gam   = (const float*)d_in[8];
    const float* bet   = (const float*)d_in[9];

    float* h      = (float*)d_out;                       // (64,2000,160)
    float* mpatch = h + (size_t)64*2000*160;             // (64,2000)

    __hip_bfloat16* wbf = (__hip_bfloat16*)d_ws;                          // [0, 40960)
    __hip_bfloat16* agm = (__hip_bfloat16*)((char*)d_ws + 40960);         // 12 KB Toeplitz A
    __hip_bfloat16* xsb = (__hip_bfloat16*)((char*)d_ws + 65536);         // 32.8 MB

    k_cvtw<<<104, 256, 0, stream>>>(wproj, w_env, w_bur, wbf, agm);
    k_pre<<<3200, 256, 0, stream>>>(X, M, syn, wdw, wpw, agm, xsb, mpatch);
    k_proj<<<1000, 256, 0, stream>>>(wbf, xsb, gam, bet, h);
}